// Round 3
// baseline (898.753 us; speedup 1.0000x reference)
//
#include <hip/hip_runtime.h>
#include <math.h>

#define B_ 16
#define C_ 256
#define H_ 128
#define W_ 128
#define HW_ (H_*W_)
#define PO 20
#define NPOOL (PO*PO)
#define MID_ 16
#define OC_ 32
#define OH_ 64
#define OW_ 64
#define BN_EPS 1e-3f

// workspace offsets in floats
#define OFF_XP     0
#define OFF_SN     1638400
#define OFF_BAR    1644800   // grid-barrier counter (inside memset range)
#define OFF_SCORE  1648896
#define OFF_TOTM   1649152
#define OFF_BNSUM  1649184
#define OFF_BNSQ   1649216
#define OFF_SMEAN  1649248
#define OFF_SMAX   1911392
#define OFF_SIGA   2173536
#define OFF_XC     2435680
#define OFF_RS     10824288
#define OFF_DOT    10828384

// adaptive-pool bin start/end for n=128 -> 20
__device__ __forceinline__ int bin_s(int p) { return (p * 128) / 20; }
__device__ __forceinline__ int bin_e(int p) { return ((p + 1) * 128 + 19) / 20; }

// Hand-rolled grid barrier: monotonic counter, one arrival per block.
// Release-add publishes this XCD's L2 (writeback); acquire-load invalidates,
// so post-barrier reads see all pre-barrier writes across XCDs.
// Deadlock-free by construction: launch_bounds(256,2) caps VGPR<=256 and LDS
// is 52KB => HW capacity >= 2 blocks/CU = 512 slots for 512 blocks (all
// resident). Bounded spin = fail-loud instead of wedging on a logic bug.
__device__ __forceinline__ void gbar(unsigned* bar, unsigned target) {
  __syncthreads();
  if (threadIdx.x == 0) {
    __threadfence();
    __hip_atomic_fetch_add(bar, 1u, __ATOMIC_RELEASE, __HIP_MEMORY_SCOPE_AGENT);
    long guard = 0;
    while (__hip_atomic_load(bar, __ATOMIC_ACQUIRE, __HIP_MEMORY_SCOPE_AGENT) < target) {
      __builtin_amdgcn_s_sleep(8);
      if (++guard > (1L << 22)) break; // ~1s escape valve; never hit when correct
    }
  }
  __syncthreads();
}

// ONE kernel, 512 blocks x 256 threads. Phase indexing identical to the
// round-1 multi-kernel versions (P1/P4/P5/P6/P7 passed there verbatim).
__global__ __launch_bounds__(256, 2) void mega(
    const float* __restrict__ x, const float* __restrict__ lw,
    const float* __restrict__ lb, const float* __restrict__ lsa_w,
    const float* __restrict__ conv_w, const float* __restrict__ conv_b,
    const float* __restrict__ gamma, const float* __restrict__ beta,
    float* __restrict__ out, float* __restrict__ ws) {
  __shared__ __attribute__((aligned(16))) float smem[13000]; // 52 KB, re-aliased per phase
  const int blk = blockIdx.x;
  const int tid = threadIdx.x;
  float* xp    = ws + OFF_XP;
  float* sn    = ws + OFF_SN;
  unsigned* bar = (unsigned*)(ws + OFF_BAR);
  float* score = ws + OFF_SCORE;
  float* totm  = ws + OFF_TOTM;
  float* bnsum = ws + OFF_BNSUM;
  float* bnsq  = ws + OFF_BNSQ;
  float* smean = ws + OFF_SMEAN;
  float* smax  = ws + OFF_SMAX;
  float* siga  = ws + OFF_SIGA;
  float* xc    = ws + OFF_XC;
  float* rsb   = ws + OFF_RS;
  float* dotb  = ws + OFF_DOT;

  // ========== P1: fused adaptive-pool + group-mean + column-sum ==========
  {
    float (*tmp)[64 * 21] = (float (*)[64 * 21])smem; // 10.5 KB double buffer
    const int b = blk >> 5, g = (blk >> 1) & 15, rh = blk & 1;
    const int hl = tid >> 2, q = tid & 3;
    const int hg = rh * 64 + hl;
    const float* rowbase = x + (size_t)(b * C_) * HW_ + (size_t)hg * W_ + q * 32;

    float4 xacc[8];
#pragma unroll
    for (int j = 0; j < 8; ++j) xacc[j] = make_float4(0.f, 0.f, 0.f, 0.f);
    float snacc = 0.f;

    for (int k = 0; k < 16; ++k) {
      const int c = g * 16 + k;
      const float4* src4 = (const float4*)(rowbase + (size_t)c * HW_);
      float bin[5];
#pragma unroll
      for (int p = 0; p < 5; ++p) bin[p] = 0.f;
#pragma unroll
      for (int j = 0; j < 8; ++j) {
        float4 v = src4[j];
        xacc[j].x += v.x; xacc[j].y += v.y; xacc[j].z += v.z; xacc[j].w += v.w;
        const float c4[4] = {v.x, v.y, v.z, v.w};
#pragma unroll
        for (int kk = 0; kk < 4; ++kk) {
          const int cc = 4 * j + kk;
#pragma unroll
          for (int p = 0; p < 5; ++p) {
            const int S = (p * 32) / 5;            // 0,6,12,19,25
            const int E = ((p + 1) * 32 + 4) / 5;  // 7,13,20,26,32
            if (cc >= S && cc < E) bin[p] += c4[kk]; // folds at compile time
          }
        }
      }
      float* tb = tmp[k & 1];
#pragma unroll
      for (int p = 0; p < 5; ++p) {
        const int S = (p * 32) / 5, E = ((p + 1) * 32 + 4) / 5;
        tb[hl * 21 + q * 5 + p] = bin[p] / (float)(E - S);
      }
      __syncthreads();
      if (tid < 200) { // 10 out rows x 20 cols for this channel
        const int ol = tid / 20, p = tid % 20;
        const int o = rh * 10 + ol;
        const int rs_ = bin_s(o), re_ = bin_e(o);
        float s = 0.f;
        for (int r = rs_; r < re_; ++r) s += tb[(r - rh * 64) * 21 + p];
        float v = s / (float)(re_ - rs_);
        xp[(size_t)(b * C_ + c) * NPOOL + o * PO + p] = v;
        snacc += v;
      }
      // single barrier per channel: buffer k reused at k+2, separated by
      // barrier k+1 (full __syncthreads drains the reads).
    }
    if (tid < 200) atomicAdd(&sn[b * NPOOL + rh * 200 + tid], snacc);
    float4* dst = (float4*)(xc + (size_t)(b * OC_ + MID_ + g) * HW_ + (size_t)hg * W_ + q * 32);
#pragma unroll
    for (int j = 0; j < 8; ++j) {
      float4 v = xacc[j];
      v.x *= 0.0625f; v.y *= 0.0625f; v.z *= 0.0625f; v.w *= 0.0625f;
      dst[j] = v;
    }
  }
  gbar(bar, 512);

  // ========== P2: per-channel rs/dot over xp (full-grid) ===================
  {
    float* snl  = smem;        // 400
    float* part = smem + 400;  // 8
    const int bb = blk >> 5, sub = blk & 31;
    const int cl = tid >> 5, lane = tid & 31;
    const int c = sub * 8 + cl;
    for (int i = tid; i < NPOOL; i += 256) snl[i] = sn[bb * NPOOL + i];
    __syncthreads();
    const float* row = xp + (size_t)(bb * C_ + c) * NPOOL;
    float rs = 0.f, dt = 0.f;
    for (int n = lane; n < NPOOL; n += 32) { // coalesced across 32 lanes
      float v = row[n];
      rs += v;
      dt += v * snl[n];
    }
#pragma unroll
    for (int o = 16; o > 0; o >>= 1) {
      rs += __shfl_down(rs, o, 32);
      dt += __shfl_down(dt, o, 32);
    }
    if (lane == 0) {
      rsb[bb * C_ + c] = rs;
      dotb[bb * C_ + c] = dt;
      part[cl] = rs;
    }
    __syncthreads();
    if (tid == 0) {
      float s = 0.f;
#pragma unroll
      for (int i = 0; i < 8; ++i) s += part[i];
      atomicAdd(&totm[bb], s); // accumulates sum_c rs_c
    }
  }
  gbar(bar, 1024);

  // ========== P3: z_j = lw . feat + lb, sigmoid, score =====================
  // feat_i = (dot_i - (sum_rs/400)*rs_i) / (399*256)  [S-term analytically 0]
  {
    float* rs_l  = smem;        // 256
    float* dot_l = smem + 256;  // 256
    const int bb = blk >> 5, sub = blk & 31;
    rs_l[tid]  = rsb[bb * C_ + tid];
    dot_l[tid] = dotb[bb * C_ + tid];
    __syncthreads();
    const float t = totm[bb] * (1.0f / (float)NPOOL);
    const int j = sub * 8 + (tid >> 5), lane = tid & 31;
    const float* wrow = lw + (size_t)j * C_;
    const float INV = 1.0f / ((float)(NPOOL - 1) * (float)C_);
    float z = 0.f;
#pragma unroll
    for (int i0 = 0; i0 < 8; ++i0) {
      int i = lane + 32 * i0;
      z += wrow[i] * ((dot_l[i] - t * rs_l[i]) * INV);
    }
#pragma unroll
    for (int o = 16; o > 0; o >>= 1) z += __shfl_down(z, o, 32);
    if (lane == 0) {
      float zf = z + lb[j];
      float sig = 1.0f / (1.0f + expf(-zf)); // accurate expf: score gaps ~1e-6
      atomicAdd(&score[j], sig * (1.0f / (float)B_));
    }
  }
  gbar(bar, 1536);

  // ========== P4: top-16 select (redundant per block) + build xc + mean/max
  {
    float* ss    = smem;                    // 256
    int* flag    = (int*)(smem + 256);      // 256
    int* mid_s   = (int*)(smem + 512);      // 16
    float* sc_s  = smem + 528;              // 16
    float4* ps   = (float4*)(smem + 544);   // 512 floats
    float4* pm   = (float4*)(smem + 1056);  // 512 floats
    ss[tid] = score[tid];
    __syncthreads();
    {
      float my = ss[tid];
      int rank = 0;
      for (int k = 0; k < C_; ++k) {
        float v = ss[k];
        rank += (v > my || (v == my && k < tid)) ? 1 : 0;
      }
      flag[tid] = (rank < MID_) ? 1 : 0;
      __syncthreads();
      if (rank < MID_) {
        int pos = 0;
        for (int k = 0; k < tid; ++k) pos += flag[k];
        mid_s[pos] = tid;       // ascending == jnp.sort
        sc_s[pos] = 1.0f + my;
      }
    }
    __syncthreads();
    const int p = tid & 127, s = tid >> 7;
    const int P = blk * 128 + p; // over B*HW/4 = 65536
    const int b = P >> 12, pix4 = P & 4095;
    const float4* xb = (const float4*)x + (size_t)(b * C_) * (HW_ / 4) + pix4;
    float4* xcb = (float4*)xc + (size_t)(b * OC_) * (HW_ / 4) + pix4;
    float4 ms = make_float4(0.f, 0.f, 0.f, 0.f);
    float4 mx = make_float4(-INFINITY, -INFINITY, -INFINITY, -INFINITY);
#pragma unroll
    for (int mi = 0; mi < 8; ++mi) {
      int m = s * 8 + mi;
      float4 t = xb[(size_t)mid_s[m] * (HW_ / 4)];
      float sc = sc_s[m];
      t.x *= sc; t.y *= sc; t.z *= sc; t.w *= sc;
      xcb[(size_t)m * (HW_ / 4)] = t;
      ms.x += t.x; ms.y += t.y; ms.z += t.z; ms.w += t.w;
      mx.x = fmaxf(mx.x, t.x); mx.y = fmaxf(mx.y, t.y);
      mx.z = fmaxf(mx.z, t.z); mx.w = fmaxf(mx.w, t.w);
    }
#pragma unroll
    for (int gi = 0; gi < 8; ++gi) {
      float4 t = xcb[(size_t)(MID_ + s * 8 + gi) * (HW_ / 4)];
      ms.x += t.x; ms.y += t.y; ms.z += t.z; ms.w += t.w;
      mx.x = fmaxf(mx.x, t.x); mx.y = fmaxf(mx.y, t.y);
      mx.z = fmaxf(mx.z, t.z); mx.w = fmaxf(mx.w, t.w);
    }
    if (s == 1) { ps[p] = ms; pm[p] = mx; }
    __syncthreads();
    if (s == 0) {
      float4 a = ps[p], m2 = pm[p];
      ms.x = (ms.x + a.x) * (1.f / 32.f); ms.y = (ms.y + a.y) * (1.f / 32.f);
      ms.z = (ms.z + a.z) * (1.f / 32.f); ms.w = (ms.w + a.w) * (1.f / 32.f);
      mx.x = fmaxf(mx.x, m2.x); mx.y = fmaxf(mx.y, m2.y);
      mx.z = fmaxf(mx.z, m2.z); mx.w = fmaxf(mx.w, m2.w);
      ((float4*)smean)[P] = ms;
      ((float4*)smax)[P] = mx;
    }
  }
  gbar(bar, 2048);

  // ========== P5: LSA 7x7 conv (2->1) pad 3 + sigmoid (2 chunks/block) =====
  {
    float* w0 = smem;       // 49
    float* w1 = smem + 49;  // 49
    if (tid < 49) { w0[tid] = lsa_w[tid]; w1[tid] = lsa_w[49 + tid]; }
    __syncthreads();
#pragma unroll
    for (int u = 0; u < 2; ++u) {
      int idx = (blk * 2 + u) * 256 + tid; // over B*HW
      int b = idx >> 14;
      int pix = idx & (HW_ - 1);
      int h = pix >> 7, w = pix & 127;
      const float* pmn = smean + (size_t)b * HW_;
      const float* pxm = smax + (size_t)b * HW_;
      float acc = 0.f;
      for (int kh = 0; kh < 7; ++kh) {
        int ih = h + kh - 3;
        if (ih < 0 || ih >= H_) continue;
        for (int kw = 0; kw < 7; ++kw) {
          int iw = w + kw - 3;
          if (iw < 0 || iw >= W_) continue;
          int p = ih * W_ + iw;
          acc += pmn[p] * w0[kh * 7 + kw] + pxm[p] * w1[kh * 7 + kw];
        }
      }
      siga[idx] = 1.0f / (1.0f + __expf(-acc));
    }
    __syncthreads(); // all reads of w0/w1 done before smem reuse in P6
  }
  gbar(bar, 2560);

  // ========== P6: conv 3x3 s2 p1 (32->32) + bias + BN partial sums =========
  {
    float* in_lds = smem;         // 2640 (16B aligned at offset 0)
    float* sg_lds = smem + 2640;  // 660
    float* w_lds  = smem + 3300;  // 288*33 = 9504
    const int oc = tid & 31;
    const int g = tid >> 5;
    const int b = blk >> 5;
    const int oh0 = (blk & 31) * 2;
    const int ih0 = 2 * oh0 - 1; // rows ih0..ih0+4

    for (int i = tid; i < 288 * 32; i += 256) {
      int oc_ = i / 288, rem = i % 288;
      w_lds[rem * 33 + oc_] = conv_w[i]; // stride 33: conflict-free staging
    }
    const float* sgb = siga + (size_t)b * HW_;
    for (int i = tid; i < 5 * 132; i += 256) {
      int r = i / 132, col = i % 132;
      int ih = ih0 + r, iw = col - 1;
      float v = 0.f;
      if (ih >= 0 && ih < H_ && iw >= 0 && iw < W_) v = sgb[ih * W_ + iw];
      sg_lds[i] = v;
    }

    float acc[2][8];
#pragma unroll
    for (int a = 0; a < 2; ++a)
#pragma unroll
      for (int o = 0; o < 8; ++o) acc[a][o] = 0.f;

    for (int chunk = 0; chunk < 8; ++chunk) {
      __syncthreads();
      for (int i = tid; i < 4 * 5 * 132; i += 256) {
        int icl = i / 660;
        int rem = i % 660;
        int r = rem / 132, col = rem % 132;
        int ih = ih0 + r, iw = col - 1;
        float v = 0.f;
        if (ih >= 0 && ih < H_ && iw >= 0 && iw < W_) {
          v = xc[((size_t)(b * OC_) + (chunk * 4 + icl)) * HW_ + ih * W_ + iw] * sg_lds[rem];
        }
        in_lds[i] = v;
      }
      __syncthreads();
#pragma unroll
      for (int icl = 0; icl < 4; ++icl) {
        float wr[9];
        const int wb = (chunk * 4 + icl) * 9 * 33 + oc;
#pragma unroll
        for (int t = 0; t < 9; ++t) wr[t] = w_lds[wb + t * 33];
#pragma unroll
        for (int r = 0; r < 5; ++r) {
          float f[20] __attribute__((aligned(16)));
          const float4* s4 = (const float4*)&in_lds[(icl * 5 + r) * 132 + 16 * g];
#pragma unroll
          for (int j = 0; j < 5; ++j) ((float4*)f)[j] = s4[j];
#pragma unroll
          for (int ohl = 0; ohl < 2; ++ohl) {
            const int kh = r - 2 * ohl;
            if (kh < 0 || kh > 2) continue; // compile-time after unroll
            float w0 = wr[kh * 3 + 0];
            float w1 = wr[kh * 3 + 1];
            float w2 = wr[kh * 3 + 2];
#pragma unroll
            for (int o = 0; o < 8; ++o)
              acc[ohl][o] += f[2 * o] * w0 + f[2 * o + 1] * w1 + f[2 * o + 2] * w2;
          }
        }
      }
    }

    float bias = conv_b[oc];
    float lsum = 0.f, lsq = 0.f;
    float* outp = out + ((size_t)(b * OC_) + oc) * (OH_ * OW_) + (size_t)oh0 * OW_ + g * 8;
#pragma unroll
    for (int ohl = 0; ohl < 2; ++ohl) {
      float vout[8] __attribute__((aligned(16)));
#pragma unroll
      for (int o = 0; o < 8; ++o) {
        float v = acc[ohl][o] + bias;
        vout[o] = v;
        lsum += v;
        lsq += v * v;
      }
      *((float4*)(outp + ohl * OW_)) = *(float4*)&vout[0];
      *((float4*)(outp + ohl * OW_ + 4)) = *(float4*)&vout[4];
    }
    __syncthreads(); // done reading in_lds; reuse for reduction
    in_lds[tid] = lsum;
    in_lds[256 + tid] = lsq;
    __syncthreads();
    if (tid < 32) {
      float t = 0.f, tq = 0.f;
#pragma unroll
      for (int gg = 0; gg < 8; ++gg) {
        t += in_lds[gg * 32 + tid];
        tq += in_lds[256 + gg * 32 + tid];
      }
      atomicAdd(&bnsum[tid], t);
      atomicAdd(&bnsq[tid], tq);
    }
  }
  gbar(bar, 3072);

  // ========== P7: BN finalize + apply + SiLU (4 chunks/block) ==============
  {
    float* ssc = smem;       // 32
    float* ssh = smem + 32;  // 32
    if (tid < OC_) {
      const float N = (float)(B_ * OH_ * OW_);
      float mu = bnsum[tid] / N;
      float var = bnsq[tid] / N - mu * mu; // population var (ddof=0)
      float sc = gamma[tid] / sqrtf(var + BN_EPS);
      ssc[tid] = sc;
      ssh[tid] = beta[tid] - mu * sc;
    }
    __syncthreads();
#pragma unroll
    for (int u = 0; u < 4; ++u) {
      int idx4 = (blk * 4 + u) * 256 + tid; // over out_size/4 = 524288
      int oc = (idx4 >> 10) & 31;           // 1024 float4 per (b,oc) plane
      float sc = ssc[oc], sh = ssh[oc];
      float4 v = ((float4*)out)[idx4];
      float t;
      t = v.x * sc + sh; v.x = t / (1.0f + __expf(-t));
      t = v.y * sc + sh; v.y = t / (1.0f + __expf(-t));
      t = v.z * sc + sh; v.z = t / (1.0f + __expf(-t));
      t = v.w * sc + sh; v.w = t / (1.0f + __expf(-t));
      ((float4*)out)[idx4] = v;
    }
  }
}

extern "C" void kernel_launch(void* const* d_in, const int* in_sizes, int n_in,
                              void* d_out, int out_size, void* d_ws, size_t ws_size,
                              hipStream_t stream) {
  const float* x      = (const float*)d_in[0];
  const float* lw     = (const float*)d_in[1];
  const float* lb     = (const float*)d_in[2];
  const float* lsa_w  = (const float*)d_in[3];
  const float* conv_w = (const float*)d_in[4];
  const float* conv_b = (const float*)d_in[5];
  const float* gamma  = (const float*)d_in[6];
  const float* beta   = (const float*)d_in[7];
  float* out = (float*)d_out;
  float* ws = (float*)d_ws;

  // zero: sn + bar + score + totm + bnsum + bnsq (one contiguous range)
  hipMemsetAsync(ws + OFF_SN, 0,
                 (size_t)(OFF_BNSQ + OC_ - OFF_SN) * sizeof(float), stream);

  mega<<<512, 256, 0, stream>>>(x, lw, lb, lsa_w, conv_w, conv_b,
                                gamma, beta, out, ws);
}

// Round 4
// 493.020 us; speedup vs baseline: 1.8230x; 1.8230x over previous
//
#include <hip/hip_runtime.h>
#include <math.h>

#define B_ 16
#define C_ 256
#define H_ 128
#define W_ 128
#define HW_ (H_*W_)
#define PO 20
#define NPOOL (PO*PO)
#define MID_ 16
#define OC_ 32
#define OH_ 64
#define OW_ 64
#define BN_EPS 1e-3f

// workspace offsets in floats
#define OFF_XP     0          // 16*256*400 = 1638400
#define OFF_SN     1638400    // 6400
#define OFF_SCORE  1648896    // 256
#define OFF_TOTM   1649152    // 16 (pad 32)
#define OFF_BNSUM  1649184    // 128 (4 banks x 32)
#define OFF_BNSQ   1649312    // 128
#define OFF_SMEAN  1649440    // 262144
#define OFF_SMAX   1911584    // 262144
#define OFF_SIGA   2173728    // 262144
#define OFF_XC     2435872    // 8388608
#define OFF_RS     10824480   // 4096
#define OFF_DOT    10828576   // 4096  (end 10832672 floats = 43.3 MB)

// adaptive-pool bin start/end for n=128 -> 20
__device__ __forceinline__ int bin_s(int p) { return (p * 128) / 20; }
__device__ __forceinline__ int bin_e(int p) { return ((p + 1) * 128 + 19) / 20; }

// ---------------- 1. fused pool + group-mean + column-sum -------------------
// 1024 blocks = (b:16, g:16, row-quarter rq:4) -> 4 blocks/CU resident (was 2).
// Quarter boundaries (rows 32/64/96) align exactly with pool bins 5/10/15.
// 256 threads = (kk:2 channel-of-pair, hl:32 rows, q:4 col-chunks); 8 iters
// process 2 channels each. LDS 16.5 KB, launch_bounds(256,4) caps VGPR<=128.
__global__ __launch_bounds__(256, 4) void k_pool2(const float* __restrict__ x,
                                                  float* __restrict__ xp,
                                                  float* __restrict__ sn,
                                                  float* __restrict__ xc) {
  __shared__ float smem[4224]; // max(tmp 2*2*672=2688, comb 128*33=4224)
  float (*tmp)[2][672] = (float (*)[2][672])smem; // [buf][kk][32*21]
  const int blk = blockIdx.x;
  const int b = blk >> 6, g = (blk >> 2) & 15, rq = blk & 3;
  const int tid = threadIdx.x;
  const int kk = tid >> 7, hl = (tid >> 2) & 31, q = tid & 3;
  const int hg = rq * 32 + hl;
  const float* rowbase = x + (size_t)(b * C_) * HW_ + (size_t)hg * W_ + q * 32;

  float4 xacc[8];
#pragma unroll
  for (int j = 0; j < 8; ++j) xacc[j] = make_float4(0.f, 0.f, 0.f, 0.f);
  float snacc = 0.f;
  const int kk2 = tid / 100, rem = tid % 100, ol = rem / 20, pc = rem % 20;
  const int o = rq * 5 + ol; // this thread's output row (if tid<200)

  for (int it = 0; it < 8; ++it) {
    const int c = g * 16 + 2 * it + kk;
    const float4* src4 = (const float4*)(rowbase + (size_t)c * HW_);
    float bin[5];
#pragma unroll
    for (int p = 0; p < 5; ++p) bin[p] = 0.f;
#pragma unroll
    for (int j = 0; j < 8; ++j) {
      float4 v = src4[j];
      xacc[j].x += v.x; xacc[j].y += v.y; xacc[j].z += v.z; xacc[j].w += v.w;
      const float c4[4] = {v.x, v.y, v.z, v.w};
#pragma unroll
      for (int e = 0; e < 4; ++e) {
        const int cc = 4 * j + e;
#pragma unroll
        for (int p = 0; p < 5; ++p) {
          const int S = (p * 32) / 5;            // 0,6,12,19,25
          const int E = ((p + 1) * 32 + 4) / 5;  // 7,13,20,26,32
          if (cc >= S && cc < E) bin[p] += c4[e]; // folds at compile time
        }
      }
    }
    float* tb = tmp[it & 1][kk];
#pragma unroll
    for (int p = 0; p < 5; ++p) {
      const int S = (p * 32) / 5, E = ((p + 1) * 32 + 4) / 5;
      tb[hl * 21 + q * 5 + p] = bin[p] / (float)(E - S);
    }
    __syncthreads();
    if (tid < 200) { // 2 channels x 5 out rows x 20 cols
      const int rs_ = bin_s(o), re_ = bin_e(o);
      const float* tr = tmp[it & 1][kk2];
      float s = 0.f;
      for (int r = rs_; r < re_; ++r) s += tr[(r - rq * 32) * 21 + pc];
      float v = s / (float)(re_ - rs_);
      xp[(size_t)(b * C_ + g * 16 + 2 * it + kk2) * NPOOL + o * PO + pc] = v;
      snacc += v;
    }
    // single barrier/iter: buf it&1 is rewritten at it+2, after barrier it+1
  }
  if (tid < 200) atomicAdd(&sn[b * NPOOL + o * PO + pc], snacc);
  // combine kk halves of the group-mean accumulator via LDS (stride 33:
  // banks (idx+m)%32, conflict-free), then kk=0 scales and stores.
  __syncthreads(); // all tmp reads done; smem reused
  const int idx = hl * 4 + q;
  if (kk == 1) {
#pragma unroll
    for (int j = 0; j < 8; ++j) {
      smem[idx * 33 + 4 * j + 0] = xacc[j].x;
      smem[idx * 33 + 4 * j + 1] = xacc[j].y;
      smem[idx * 33 + 4 * j + 2] = xacc[j].z;
      smem[idx * 33 + 4 * j + 3] = xacc[j].w;
    }
  }
  __syncthreads();
  if (kk == 0) {
    float4* dst = (float4*)(xc + (size_t)(b * OC_ + MID_ + g) * HW_ + (size_t)hg * W_ + q * 32);
#pragma unroll
    for (int j = 0; j < 8; ++j) {
      float4 v = xacc[j];
      v.x = (v.x + smem[idx * 33 + 4 * j + 0]) * 0.0625f;
      v.y = (v.y + smem[idx * 33 + 4 * j + 1]) * 0.0625f;
      v.z = (v.z + smem[idx * 33 + 4 * j + 2]) * 0.0625f;
      v.w = (v.w + smem[idx * 33 + 4 * j + 3]) * 0.0625f;
      dst[j] = v;
    }
  }
}

// ---------------- 2. per-channel rs/dot over xp (512 blocks, proven) -------
__global__ __launch_bounds__(256) void k_rsdot(const float* __restrict__ xp,
                                               const float* __restrict__ sn,
                                               float* __restrict__ rsb,
                                               float* __restrict__ dotb,
                                               float* __restrict__ totm) {
  __shared__ float snl[NPOOL];
  __shared__ float part[8];
  const int blk = blockIdx.x, tid = threadIdx.x;
  const int bb = blk >> 5, sub = blk & 31;
  const int cl = tid >> 5, lane = tid & 31;
  const int c = sub * 8 + cl;
  for (int i = tid; i < NPOOL; i += 256) snl[i] = sn[bb * NPOOL + i];
  __syncthreads();
  const float* row = xp + (size_t)(bb * C_ + c) * NPOOL;
  float rs = 0.f, dt = 0.f;
  for (int n = lane; n < NPOOL; n += 32) {
    float v = row[n];
    rs += v;
    dt += v * snl[n];
  }
#pragma unroll
  for (int o = 16; o > 0; o >>= 1) {
    rs += __shfl_down(rs, o, 32);
    dt += __shfl_down(dt, o, 32);
  }
  if (lane == 0) {
    rsb[bb * C_ + c] = rs;
    dotb[bb * C_ + c] = dt;
    part[cl] = rs;
  }
  __syncthreads();
  if (tid == 0) {
    float s = 0.f;
#pragma unroll
    for (int i = 0; i < 8; ++i) s += part[i];
    atomicAdd(&totm[bb], s); // accumulates sum_c rs_c
  }
}

// ---------------- 3. attn z_j + sigmoid + score (512 blocks, proven) -------
// feat_i = (dot_i - (sum_rs/400)*rs_i) / (399*256)  [S-term analytically 0]
__global__ __launch_bounds__(256) void k_attn2(const float* __restrict__ rsb,
                                               const float* __restrict__ dotb,
                                               const float* __restrict__ totm,
                                               const float* __restrict__ lw,
                                               const float* __restrict__ lb,
                                               float* __restrict__ score) {
  __shared__ float rs_l[C_], dot_l[C_];
  const int blk = blockIdx.x, tid = threadIdx.x;
  const int bb = blk >> 5, sub = blk & 31;
  rs_l[tid]  = rsb[bb * C_ + tid];
  dot_l[tid] = dotb[bb * C_ + tid];
  __syncthreads();
  const float t = totm[bb] * (1.0f / (float)NPOOL);
  const int j = sub * 8 + (tid >> 5), lane = tid & 31;
  const float* wrow = lw + (size_t)j * C_;
  const float INV = 1.0f / ((float)(NPOOL - 1) * (float)C_);
  float z = 0.f;
#pragma unroll
  for (int i0 = 0; i0 < 8; ++i0) {
    int i = lane + 32 * i0;
    z += wrow[i] * ((dot_l[i] - t * rs_l[i]) * INV);
  }
#pragma unroll
  for (int o = 16; o > 0; o >>= 1) z += __shfl_down(z, o, 32);
  if (lane == 0) {
    float zf = z + lb[j];
    float sig = 1.0f / (1.0f + expf(-zf)); // accurate expf: score gaps ~1e-6
    atomicAdd(&score[j], sig * (1.0f / (float)B_));
  }
}

// ---------------- 4. top-16 select + build xc + channel mean/max -----------
// 1024 blocks (was 512): 64 float4-positions/block, 4-way channel split.
__global__ __launch_bounds__(256) void k_build(const float* __restrict__ x,
                                               const float* __restrict__ score,
                                               float* __restrict__ xc,
                                               float* __restrict__ smean,
                                               float* __restrict__ smax) {
  __shared__ float ss[C_];
  __shared__ int flag[C_];
  __shared__ int mid_s[MID_];
  __shared__ float sc_s[MID_];
  __shared__ float4 ps[3 * 64], pm[3 * 64];
  const int blk = blockIdx.x, tid = threadIdx.x;
  ss[tid] = score[tid];
  __syncthreads();
  {
    float my = ss[tid];
    int rank = 0;
    for (int k = 0; k < C_; ++k) {
      float v = ss[k];
      rank += (v > my || (v == my && k < tid)) ? 1 : 0;
    }
    flag[tid] = (rank < MID_) ? 1 : 0;
    __syncthreads();
    if (rank < MID_) {
      int pos = 0;
      for (int k = 0; k < tid; ++k) pos += flag[k];
      mid_s[pos] = tid;       // ascending == jnp.sort
      sc_s[pos] = 1.0f + my;
    }
  }
  __syncthreads();
  const int p = tid & 63, s = tid >> 6; // 4 channel-groups
  const int P = blk * 64 + p;           // over B*HW/4 = 65536
  const int b = P >> 12, pix4 = P & 4095;
  const float4* xb = (const float4*)x + (size_t)(b * C_) * (HW_ / 4) + pix4;
  float4* xcb = (float4*)xc + (size_t)(b * OC_) * (HW_ / 4) + pix4;
  float4 ms = make_float4(0.f, 0.f, 0.f, 0.f);
  float4 mx = make_float4(-INFINITY, -INFINITY, -INFINITY, -INFINITY);
#pragma unroll
  for (int mi = 0; mi < 4; ++mi) {
    int m = s * 4 + mi;
    float4 t = xb[(size_t)mid_s[m] * (HW_ / 4)];
    float sc = sc_s[m];
    t.x *= sc; t.y *= sc; t.z *= sc; t.w *= sc;
    xcb[(size_t)m * (HW_ / 4)] = t;
    ms.x += t.x; ms.y += t.y; ms.z += t.z; ms.w += t.w;
    mx.x = fmaxf(mx.x, t.x); mx.y = fmaxf(mx.y, t.y);
    mx.z = fmaxf(mx.z, t.z); mx.w = fmaxf(mx.w, t.w);
  }
#pragma unroll
  for (int gi = 0; gi < 4; ++gi) {
    float4 t = xcb[(size_t)(MID_ + s * 4 + gi) * (HW_ / 4)];
    ms.x += t.x; ms.y += t.y; ms.z += t.z; ms.w += t.w;
    mx.x = fmaxf(mx.x, t.x); mx.y = fmaxf(mx.y, t.y);
    mx.z = fmaxf(mx.z, t.z); mx.w = fmaxf(mx.w, t.w);
  }
  if (s > 0) { ps[(s - 1) * 64 + p] = ms; pm[(s - 1) * 64 + p] = mx; }
  __syncthreads();
  if (s == 0) {
#pragma unroll
    for (int k = 0; k < 3; ++k) {
      float4 a = ps[k * 64 + p], m2 = pm[k * 64 + p];
      ms.x += a.x; ms.y += a.y; ms.z += a.z; ms.w += a.w;
      mx.x = fmaxf(mx.x, m2.x); mx.y = fmaxf(mx.y, m2.y);
      mx.z = fmaxf(mx.z, m2.z); mx.w = fmaxf(mx.w, m2.w);
    }
    ms.x *= (1.f / 32.f); ms.y *= (1.f / 32.f);
    ms.z *= (1.f / 32.f); ms.w *= (1.f / 32.f);
    ((float4*)smean)[P] = ms;
    ((float4*)smax)[P] = mx;
  }
}

// ---------------- 5. LSA 7x7 conv (2->1) pad 3 + sigmoid -------------------
__global__ __launch_bounds__(256) void k_lsa(const float* __restrict__ smean,
                                             const float* __restrict__ smax,
                                             const float* __restrict__ lsa_w,
                                             float* __restrict__ siga) {
  __shared__ float w0[49], w1[49];
  if (threadIdx.x < 49) {
    w0[threadIdx.x] = lsa_w[threadIdx.x];
    w1[threadIdx.x] = lsa_w[49 + threadIdx.x];
  }
  __syncthreads();
  int idx = blockIdx.x * 256 + threadIdx.x; // over B*HW
  int b = idx >> 14;
  int pix = idx & (HW_ - 1);
  int h = pix >> 7, w = pix & 127;
  const float* pm = smean + (size_t)b * HW_;
  const float* px = smax + (size_t)b * HW_;
  float acc = 0.f;
  for (int kh = 0; kh < 7; ++kh) {
    int ih = h + kh - 3;
    if (ih < 0 || ih >= H_) continue;
    for (int kw = 0; kw < 7; ++kw) {
      int iw = w + kw - 3;
      if (iw < 0 || iw >= W_) continue;
      int p = ih * W_ + iw;
      acc += pm[p] * w0[kh * 7 + kw] + px[p] * w1[kh * 7 + kw];
    }
  }
  siga[idx] = 1.0f / (1.0f + __expf(-acc));
}

// ---------------- 6. conv 3x3 s2 p1 (32->32) + bias + BN partials ----------
// 1024 blocks (was 512): ONE output row per block. Weights staged per-4-ic
// chunk -> LDS 12.7 KB (was 49) -> 4+ blocks/CU. BN atomics banked x4.
__global__ __launch_bounds__(256, 4) void k_conv(const float* __restrict__ xc,
                                                 const float* __restrict__ siga,
                                                 const float* __restrict__ conv_w,
                                                 const float* __restrict__ conv_b,
                                                 float* __restrict__ out,
                                                 float* __restrict__ bnsum,
                                                 float* __restrict__ bnsq) {
  __shared__ __attribute__((aligned(16))) float in_lds[4 * 3 * 132]; // 1584
  __shared__ float sg_lds[3 * 132];                                  // 396
  __shared__ float w_lds[4 * 9 * 33];                                // 1188
  const int tid = threadIdx.x;
  const int oc = tid & 31;
  const int g = tid >> 5;
  const int b = blockIdx.x >> 6;
  const int oh = blockIdx.x & 63;
  const int ih0 = 2 * oh - 1; // rows ih0..ih0+2

  const float* sgb = siga + (size_t)b * HW_;
  for (int i = tid; i < 3 * 132; i += 256) {
    int r = i / 132, col = i % 132;
    int ih = ih0 + r, iw = col - 1;
    float v = 0.f;
    if (ih >= 0 && ih < H_ && iw >= 0 && iw < W_) v = sgb[ih * W_ + iw];
    sg_lds[i] = v;
  }

  float acc[8];
#pragma unroll
  for (int o = 0; o < 8; ++o) acc[o] = 0.f;

  for (int chunk = 0; chunk < 8; ++chunk) {
    __syncthreads();
    // stage 4 input channels (xsiga product) + their weights
    for (int i = tid; i < 4 * 3 * 132; i += 256) {
      int icl = i / 396;
      int rem = i % 396;
      int r = rem / 132, col = rem % 132;
      int ih = ih0 + r, iw = col - 1;
      float v = 0.f;
      if (ih >= 0 && ih < H_ && iw >= 0 && iw < W_) {
        v = xc[((size_t)(b * OC_) + (chunk * 4 + icl)) * HW_ + ih * W_ + iw] * sg_lds[rem];
      }
      in_lds[i] = v;
    }
    for (int i = tid; i < 4 * 9 * 32; i += 256) {
      int oc_ = i & 31, t = i >> 5; // t = icl*9 + k9
      int icl = t / 9, k9 = t % 9;
      w_lds[t * 33 + oc_] = conv_w[(size_t)oc_ * 288 + (chunk * 4 + icl) * 9 + k9];
    }
    __syncthreads();
#pragma unroll
    for (int icl = 0; icl < 4; ++icl) {
      float wr[9];
#pragma unroll
      for (int t = 0; t < 9; ++t) wr[t] = w_lds[(icl * 9 + t) * 33 + oc];
#pragma unroll
      for (int r = 0; r < 3; ++r) { // kh == r for the single output row
        float f[20] __attribute__((aligned(16)));
        const float4* s4 = (const float4*)&in_lds[(icl * 3 + r) * 132 + 16 * g];
#pragma unroll
        for (int j = 0; j < 5; ++j) ((float4*)f)[j] = s4[j];
        float w0 = wr[r * 3 + 0];
        float w1 = wr[r * 3 + 1];
        float w2 = wr[r * 3 + 2];
#pragma unroll
        for (int o = 0; o < 8; ++o)
          acc[o] += f[2 * o] * w0 + f[2 * o + 1] * w1 + f[2 * o + 2] * w2;
      }
    }
  }

  float bias = conv_b[oc];
  float lsum = 0.f, lsq = 0.f;
  float* outp = out + ((size_t)(b * OC_) + oc) * (OH_ * OW_) + (size_t)oh * OW_ + g * 8;
  {
    float vout[8] __attribute__((aligned(16)));
#pragma unroll
    for (int o = 0; o < 8; ++o) {
      float v = acc[o] + bias;
      vout[o] = v;
      lsum += v;
      lsq += v * v;
    }
    *((float4*)(outp)) = *(float4*)&vout[0];
    *((float4*)(outp + 4)) = *(float4*)&vout[4];
  }
  __syncthreads(); // done reading in_lds; reuse for reduction
  in_lds[tid] = lsum;
  in_lds[256 + tid] = lsq;
  __syncthreads();
  if (tid < 32) {
    float t = 0.f, tq = 0.f;
#pragma unroll
    for (int gg = 0; gg < 8; ++gg) {
      t += in_lds[gg * 32 + tid];
      tq += in_lds[256 + gg * 32 + tid];
    }
    const int bank = (blockIdx.x & 3) * 32;
    atomicAdd(&bnsum[bank + tid], t);
    atomicAdd(&bnsq[bank + tid], tq);
  }
}

// ---------------- 7. BN finalize (4 banks) + apply + SiLU ------------------
__global__ __launch_bounds__(256) void k_apply(float* __restrict__ out,
                                               const float* __restrict__ sum,
                                               const float* __restrict__ sq,
                                               const float* __restrict__ gamma,
                                               const float* __restrict__ beta) {
  __shared__ float ssc[OC_], ssh[OC_];
  if (threadIdx.x < OC_) {
    int i = threadIdx.x;
    const float N = (float)(B_ * OH_ * OW_);
    float s = sum[i] + sum[32 + i] + sum[64 + i] + sum[96 + i];
    float q = sq[i] + sq[32 + i] + sq[64 + i] + sq[96 + i];
    float mu = s / N;
    float var = q / N - mu * mu; // population var (ddof=0)
    float sc = gamma[i] / sqrtf(var + BN_EPS);
    ssc[i] = sc;
    ssh[i] = beta[i] - mu * sc;
  }
  __syncthreads();
  int idx4 = blockIdx.x * 256 + threadIdx.x; // over out_size/4 = 524288
  int oc = (idx4 >> 10) & 31;                // 1024 float4 per (b,oc) plane
  float sc = ssc[oc], sh = ssh[oc];
  float4 v = ((float4*)out)[idx4];
  float t;
  t = v.x * sc + sh; v.x = t / (1.0f + __expf(-t));
  t = v.y * sc + sh; v.y = t / (1.0f + __expf(-t));
  t = v.z * sc + sh; v.z = t / (1.0f + __expf(-t));
  t = v.w * sc + sh; v.w = t / (1.0f + __expf(-t));
  ((float4*)out)[idx4] = v;
}

extern "C" void kernel_launch(void* const* d_in, const int* in_sizes, int n_in,
                              void* d_out, int out_size, void* d_ws, size_t ws_size,
                              hipStream_t stream) {
  const float* x      = (const float*)d_in[0];
  const float* lw     = (const float*)d_in[1];
  const float* lb     = (const float*)d_in[2];
  const float* lsa_w  = (const float*)d_in[3];
  const float* conv_w = (const float*)d_in[4];
  const float* conv_b = (const float*)d_in[5];
  const float* gamma  = (const float*)d_in[6];
  const float* beta   = (const float*)d_in[7];
  float* out = (float*)d_out;
  float* ws = (float*)d_ws;

  // zero: sn .. score/totm/bnsum/bnsq (one contiguous range incl. small gap)
  hipMemsetAsync(ws + OFF_SN, 0,
                 (size_t)(OFF_BNSQ + 128 - OFF_SN) * sizeof(float), stream);

  k_pool2<<<1024, 256, 0, stream>>>(x, ws + OFF_XP, ws + OFF_SN, ws + OFF_XC);
  k_rsdot<<<512, 256, 0, stream>>>(ws + OFF_XP, ws + OFF_SN,
                                   ws + OFF_RS, ws + OFF_DOT, ws + OFF_TOTM);
  k_attn2<<<512, 256, 0, stream>>>(ws + OFF_RS, ws + OFF_DOT, ws + OFF_TOTM,
                                   lw, lb, ws + OFF_SCORE);
  k_build<<<1024, 256, 0, stream>>>(x, ws + OFF_SCORE, ws + OFF_XC,
                                    ws + OFF_SMEAN, ws + OFF_SMAX);
  k_lsa<<<1024, 256, 0, stream>>>(ws + OFF_SMEAN, ws + OFF_SMAX, lsa_w, ws + OFF_SIGA);
  k_conv<<<1024, 256, 0, stream>>>(ws + OFF_XC, ws + OFF_SIGA, conv_w, conv_b, out,
                                   ws + OFF_BNSUM, ws + OFF_BNSQ);
  k_apply<<<2048, 256, 0, stream>>>(out, ws + OFF_BNSUM, ws + OFF_BNSQ, gamma, beta);
}